// Round 10
// baseline (1305.210 us; speedup 1.0000x reference)
//
#include <hip/hip_runtime.h>
#include <hip/hip_bf16.h>
#include <math.h>

#define B_ 32
#define T_ 128
#define V_ 32000
#define D_ 512
#define H_ 512

typedef __attribute__((ext_vector_type(8))) short bf16x8;
typedef __attribute__((ext_vector_type(4))) float f32x4;
typedef __attribute__((ext_vector_type(2))) unsigned long long u64x2;

#define AS1 __attribute__((address_space(1)))
#define AS3 __attribute__((address_space(3)))

__device__ __forceinline__ unsigned short f2bf(float x) {
  unsigned int b = __float_as_uint(x);
  return (unsigned short)((b + 0x7FFFu + ((b >> 16) & 1u)) >> 16);
}
__device__ __forceinline__ float bf2f(unsigned short u) {
  return __uint_as_float(((unsigned int)u) << 16);
}
__device__ __forceinline__ float sigm(float x) { return 1.0f / (1.0f + __expf(-x)); }
__device__ __forceinline__ float tanh_fast(float x) { return 1.0f - 2.0f / (__expf(2.0f * x) + 1.0f); }

__device__ __forceinline__ unsigned long long ald(const unsigned long long* p) {
  return __hip_atomic_load(p, __ATOMIC_RELAXED, __HIP_MEMORY_SCOPE_AGENT);
}
__device__ __forceinline__ bool tags2(unsigned long long d, unsigned want) {
  return (((unsigned)(d >> 16) & 0xFFFFu) == want) && (((unsigned)(d >> 48)) == want);
}

// ---------------- embedding gather -> bf16
__global__ __launch_bounds__(64) void embed_bf_kernel(const int* __restrict__ dst,
                                                      const float* __restrict__ E,
                                                      unsigned short* __restrict__ embbf) {
  int rt = blockIdx.x;           // t*32 + b
  int t = rt >> 5, b = rt & 31;
  int v = dst[b * T_ + t];
  const float4* src = (const float4*)(E + (size_t)v * D_);
  ushort4* d = (ushort4*)(embbf + (size_t)rt * D_);
  #pragma unroll
  for (int r = 0; r < 2; ++r) {
    float4 x = src[threadIdx.x + r * 64];
    ushort4 o; o.x = f2bf(x.x); o.y = f2bf(x.y); o.z = f2bf(x.z); o.w = f2bf(x.w);
    d[threadIdx.x + r * 64] = o;
  }
}

// ---------------- generic f32 -> bf16
__global__ void cvt_kernel(const float* __restrict__ in, unsigned short* __restrict__ out, int n4) {
  int stride = gridDim.x * blockDim.x;
  for (int i = blockIdx.x * blockDim.x + threadIdx.x; i < n4; i += stride) {
    float4 v = ((const float4*)in)[i];
    ushort4 o; o.x = f2bf(v.x); o.y = f2bf(v.y); o.z = f2bf(v.z); o.w = f2bf(v.w);
    ((ushort4*)out)[i] = o;
  }
}

// ---------------- W1bf[r][c] = bf16(Wih[r][c]), c<512 (row stride 1024)
__global__ void cvt_w1_kernel(const float* __restrict__ Wih, unsigned short* __restrict__ W1bf, int n4) {
  int stride = gridDim.x * blockDim.x;
  for (int i = blockIdx.x * blockDim.x + threadIdx.x; i < n4; i += stride) {
    int flat = i * 4;
    int r = flat >> 9, c = flat & 511;
    float4 v = *(const float4*)(Wih + (size_t)r * 1024 + c);
    ushort4 o; o.x = f2bf(v.x); o.y = f2bf(v.y); o.z = f2bf(v.z); o.w = f2bf(v.w);
    ((ushort4*)W1bf)[i] = o;
  }
}

// ---------------- seed tagged h0: htag[0][b][k] = (tag 0)<<16 | bf16(h0)
__global__ void seed_h0_kernel(const float* __restrict__ h0, unsigned int* __restrict__ htag) {
  int i = blockIdx.x * 256 + threadIdx.x;    // 0..16383
  htag[i] = (unsigned int)f2bf(h0[i]);
}

// ---------------- Wr rows reordered for lane-local epilogue:
// out_row = bid*128 + k_loc*4 + gate  (gate = grow>>9, kg = grow&511)
// per-row 16B-chunk swizzle: chunk ^= (out_row & 7)
__global__ void wr_prep_swz_kernel(const float* __restrict__ Wih, const float* __restrict__ Whh,
                                   unsigned short* __restrict__ Wrs, int n4) {
  int stride = gridDim.x * blockDim.x;
  for (int i = blockIdx.x * blockDim.x + threadIdx.x; i < n4; i += stride) {
    int flat = i * 4;
    int grow = flat >> 9, k = flat & 511;
    float4 a = *(const float4*)(Wih + (size_t)grow * 1024 + 512 + k);
    float4 b = ((const float4*)Whh)[i];
    ushort4 o;
    o.x = f2bf(a.x + b.x); o.y = f2bf(a.y + b.y); o.z = f2bf(a.z + b.z); o.w = f2bf(a.w + b.w);
    int gate = grow >> 9, kgl = grow & 511;
    int orow = (kgl >> 5) * 128 + (kgl & 31) * 4 + gate;
    int chunk = (k >> 3) ^ (orow & 7);
    *(ushort4*)(Wrs + (size_t)orow * 512 + chunk * 8 + (k & 7)) = o;
  }
}

// ---------------- pre-GEMM: preA3[t][kg][b][gate] = bf16(emb . W1 + bias)
__global__ __launch_bounds__(256) void gemm_pre_kernel(
    const unsigned short* __restrict__ A,
    const unsigned short* __restrict__ Bm,
    const float* __restrict__ bih, const float* __restrict__ bhh,
    unsigned short* __restrict__ preA3)
{
  __shared__ unsigned short ldsA[2][128 * 32];
  __shared__ unsigned short ldsB[2][128 * 32];
  const int tid = threadIdx.x;
  const int lane = tid & 63;
  const int wid = tid >> 6;
  const int wm = wid >> 1, wn = wid & 1;
  const int m0 = blockIdx.y * 128;
  const int n0 = blockIdx.x * 128;
  const int srow = lane >> 2;
  const int scol = (lane & 3) * 8;

  f32x4 acc[4][4] = {};
  const int NK = 512 / 32;

  auto stage = [&](int kk, int buf) {
    const int k0 = kk * 32;
    #pragma unroll
    for (int c = 0; c < 2; ++c) {
      const int r = wid * 32 + c * 16;
      const unsigned short* sa = A  + (size_t)(m0 + r + srow) * 512 + k0 + scol;
      const unsigned short* sb = Bm + (size_t)(n0 + r + srow) * 512 + k0 + scol;
      __builtin_amdgcn_global_load_lds((const AS1 void*)sa, (AS3 void*)&ldsA[buf][r * 32], 16, 0, 0);
      __builtin_amdgcn_global_load_lds((const AS1 void*)sb, (AS3 void*)&ldsB[buf][r * 32], 16, 0, 0);
    }
  };

  stage(0, 0);
  __syncthreads();

  const int rl = lane & 15;
  const int kb = lane >> 4;

  for (int kk = 0; kk < NK; ++kk) {
    const int buf = kk & 1;
    if (kk + 1 < NK) stage(kk + 1, buf ^ 1);
    const bf16x8* Af = (const bf16x8*)&ldsA[buf][0];
    const bf16x8* Bf = (const bf16x8*)&ldsB[buf][0];
    bf16x8 av[4], bv[4];
    #pragma unroll
    for (int mi = 0; mi < 4; ++mi) av[mi] = Af[(wm * 64 + mi * 16 + rl) * 4 + kb];
    #pragma unroll
    for (int ni = 0; ni < 4; ++ni) bv[ni] = Bf[(wn * 64 + ni * 16 + rl) * 4 + kb];
    #pragma unroll
    for (int mi = 0; mi < 4; ++mi)
      #pragma unroll
      for (int ni = 0; ni < 4; ++ni)
        acc[mi][ni] = __builtin_amdgcn_mfma_f32_16x16x32_bf16(av[mi], bv[ni], acc[mi][ni], 0, 0, 0);
    __syncthreads();
  }

  const int rb = (lane >> 4) * 4;
  #pragma unroll
  for (int mi = 0; mi < 4; ++mi)
    #pragma unroll
    for (int ni = 0; ni < 4; ++ni) {
      int mbase = m0 + wm * 64 + mi * 16 + rb;
      int col   = n0 + wn * 64 + ni * 16 + rl;
      int gate = col >> 9, kg = col & 511;
      int tt = mbase >> 5, bb0 = mbase & 31;
      float bb = bih[col] + bhh[col];
      #pragma unroll
      for (int j = 0; j < 4; ++j)
        preA3[(((size_t)tt * 512 + kg) * 32 + bb0 + j) * 4 + gate] = f2bf(acc[mi][ni][j] + bb);
    }
}

// ---------------- preA3[t=0][kg][:][gate] += (out0 - h0) @ W2^T  (row r = grow)
__global__ __launch_bounds__(256) void delta0_kernel(const float* __restrict__ Wih,
                                                     const float* __restrict__ out0,
                                                     const float* __restrict__ h0,
                                                     unsigned short* __restrict__ preA3) {
  const int r = blockIdx.x;
  const int tid = threadIdx.x;
  const int b = tid >> 3, seg = tid & 7;
  __shared__ float red[32][9];
  const float4* o4 = (const float4*)(out0 + (size_t)b * 512 + seg * 64);
  const float4* h4 = (const float4*)(h0 + (size_t)b * 512 + seg * 64);
  const float4* w4 = (const float4*)(Wih + (size_t)r * 1024 + 512 + seg * 64);
  float s = 0.f;
  #pragma unroll
  for (int j = 0; j < 16; ++j) {
    float4 o = o4[j], h = h4[j], w = w4[j];
    s += (o.x - h.x) * w.x + (o.y - h.y) * w.y + (o.z - h.z) * w.z + (o.w - h.w) * w.w;
  }
  red[b][seg] = s;
  __syncthreads();
  if (tid < 32) {
    float t = 0.f;
    #pragma unroll
    for (int j = 0; j < 8; ++j) t += red[tid][j];
    int gate = r >> 9, kgl = r & 511;
    unsigned short* p = preA3 + ((size_t)kgl * 32 + tid) * 4 + gate;
    *p = f2bf(bf2f(*p) + t);
  }
}

// ---------------- persistent LSTM, 16 blocks x 1024 threads, tagged exchange.
// htag[2][32][512] u32: word = (step_tag << 16) | bf16(h). Consumers verify tags
// inline (no flag round-trip, no producer drain); next phase's loads preloaded
// under current phase's compute. Raw s_barriers (no vmcnt drain).
__global__ __launch_bounds__(1024) void lstm_persist_tag_kernel(
    const unsigned short* __restrict__ Wrs,   // [2048][512] reordered+swizzled bf16
    const unsigned short* __restrict__ preA3, // [T][512][32][4] bf16 (bias folded)
    const float* __restrict__ c0,             // [32][512] f32
    unsigned int* __restrict__ htag,          // [2][32][512] u32 tagged h
    unsigned short* __restrict__ Abf)         // [B*T][512] bf16
{
  __shared__ unsigned short wlds[128 * 512];        // 128 KB, resident
  __shared__ __align__(16) char hexch[16 * 1024];   // 16 KB half-batch h tile
  const int tid = threadIdx.x, bid = blockIdx.x;
  const int lane = tid & 63, wid = tid >> 6;

  // stage 128 reordered W rows once (pre-swizzled source, linear LDS dest)
  #pragma unroll
  for (int it = 0; it < 8; ++it) {
    int r = it * 16 + wid;
    const unsigned short* src = Wrs + ((size_t)bid * 128 + r) * 512 + lane * 8;
    __builtin_amdgcn_global_load_lds((const AS1 void*)src, (AS3 void*)&wlds[r * 512], 16, 0, 0);
  }

  const int half = wid >> 3;                 // waves 0-7: half A, 8-15: half B
  const int rt = wid & 7;
  const int q = lane >> 4, rl = lane & 15;
  const int kg = bid * 32 + rt * 4 + q;      // this lane's k-slot
  const int b = half * 16 + rl;              // this lane's batch
  float c_reg = c0[(size_t)b * 512 + kg];

  const int row = rt * 16 + rl;
  const char* wbase = (const char*)wlds + row * 1024;
  const int rx = (row & 7) << 4;
  const char* hbase = hexch + rl * 1024;
  const int hx = (rl & 7) << 4;

  // stage role: wave wid stages batch (ph*16 + wid) -> hexch row wid
  char* sbase = hexch + wid * 1024;
  const int sb = lane * 16;
  const int srx = (wid & 7) << 4;

  unsigned long long d0, d1, d2, d3;
  auto issue = [&](int p) {
    const int tt = p >> 1, pph = p & 1;
    const unsigned long long* hs =
        (const unsigned long long*)(htag + ((size_t)((tt & 1) * 32) + pph * 16 + wid) * 512)
        + lane * 4;
    d0 = ald(hs + 0); d1 = ald(hs + 1); d2 = ald(hs + 2); d3 = ald(hs + 3);
  };

  issue(0);
  __syncthreads();   // W staging drained (vmcnt), block aligned

  for (int p = 0; p < 2 * T_; ++p) {
    const int t = p >> 1, ph = p & 1;
    const unsigned want = (unsigned)t;

    // verify preloaded tags; retry (rare in steady state)
    {
      unsigned spins = 0;
      while (!(tags2(d0, want) && tags2(d1, want) && tags2(d2, want) && tags2(d3, want))) {
        issue(p);
        if (++spins > 1000000u) break;   // bailout: fail validation, don't hang
      }
    }
    // strip tags -> 8 bf16 = 16 B, swizzled LDS write
    {
      unsigned long long w0 = (d0 & 0xFFFFull) | (((d0 >> 32) & 0xFFFFull) << 16)
                            | ((d1 & 0xFFFFull) << 32) | (((d1 >> 32) & 0xFFFFull) << 48);
      unsigned long long w1 = (d2 & 0xFFFFull) | (((d2 >> 32) & 0xFFFFull) << 16)
                            | ((d3 & 0xFFFFull) << 32) | (((d3 >> 32) & 0xFFFFull) << 48);
      u64x2 w; w[0] = w0; w[1] = w1;
      *(u64x2*)(sbase + (sb ^ srx)) = w;
    }

    unsigned long long pre = 0;
    if (half == ph)
      pre = *(const unsigned long long*)(preA3 + (((size_t)t * 512 + kg) * 32 + b) * 4);

    if (p + 1 < 2 * T_) issue(p + 1);   // preload next phase under this phase's compute

    __builtin_amdgcn_sched_barrier(0);
    __builtin_amdgcn_s_barrier();
    __builtin_amdgcn_sched_barrier(0);

    if (half == ph) {
      f32x4 acc = {}, acc2 = {};
      #pragma unroll
      for (int kk = 0; kk < 16; kk += 2) {
        int k0 = kk * 32 + q * 8;
        int k1 = k0 + 32;
        bf16x8 av0 = *(const bf16x8*)(wbase + ((k0 * 2) ^ rx));
        bf16x8 bv0 = *(const bf16x8*)(hbase + ((k0 * 2) ^ hx));
        bf16x8 av1 = *(const bf16x8*)(wbase + ((k1 * 2) ^ rx));
        bf16x8 bv1 = *(const bf16x8*)(hbase + ((k1 * 2) ^ hx));
        acc  = __builtin_amdgcn_mfma_f32_16x16x32_bf16(av0, bv0, acc, 0, 0, 0);
        acc2 = __builtin_amdgcn_mfma_f32_16x16x32_bf16(av1, bv1, acc2, 0, 0, 0);
      }
      // lane-local epilogue: acc[j] = gate j pre-activation for (kg, b)
      float g0 = acc[0] + acc2[0] + bf2f((unsigned short)(pre));
      float g1 = acc[1] + acc2[1] + bf2f((unsigned short)(pre >> 16));
      float g2 = acc[2] + acc2[2] + bf2f((unsigned short)(pre >> 32));
      float g3 = acc[3] + acc2[3] + bf2f((unsigned short)(pre >> 48));
      float iv = sigm(g0), fv = sigm(g1), gv = tanh_fast(g2), ov = sigm(g3);
      float cn = fv * c_reg + iv * gv;
      c_reg = cn;
      float hn = ov * tanh_fast(cn);
      unsigned myw = ((unsigned)(t + 1) << 16) | (unsigned)f2bf(hn);
      unsigned pw = (unsigned)__shfl((int)myw, lane + 16);   // partner k-slot (q+1)
      if ((q & 1) == 0) {
        unsigned long long pairT = (unsigned long long)myw | ((unsigned long long)pw << 32);
        __hip_atomic_store(
            (unsigned long long*)(htag + ((size_t)(((t + 1) & 1) * 32) + b) * 512 + kg),
            pairT, __ATOMIC_RELAXED, __HIP_MEMORY_SCOPE_AGENT);
        unsigned pairA = (myw & 0xFFFFu) | (pw << 16);
        *(unsigned*)(Abf + ((size_t)b * T_ + t) * 512 + kg) = pairA;
      }
    }

    __builtin_amdgcn_sched_barrier(0);
    __builtin_amdgcn_s_barrier();
    __builtin_amdgcn_sched_barrier(0);
  }
}

// ---------------- projection GEMM (swizzled LDS, nt C stores) + softmax partials
// grid (32 m-tiles [x, fast], 250 n-tiles [y]) -> consecutive blocks share B panel.
__global__ __launch_bounds__(256) void gemm_kernel(
    const unsigned short* __restrict__ A,
    const unsigned short* __restrict__ Bm,
    float* __restrict__ C,
    float* __restrict__ pmax, float* __restrict__ psum)
{
  __shared__ unsigned short ldsA[2][128 * 32];
  __shared__ unsigned short ldsB[2][128 * 32];
  __shared__ float smax[2][128];
  __shared__ float ssum[2][128];
  const int tid = threadIdx.x;
  const int lane = tid & 63;
  const int wid = tid >> 6;
  const int wm = wid >> 1, wn = wid & 1;
  const int m0 = blockIdx.x * 128;
  const int n0 = blockIdx.y * 128;
  const int srow = lane >> 2;

  f32x4 acc[4][4] = {};
  const int NK = 512 / 32;

  // swizzle: LDS chunk c of row r holds global chunk c ^ ((r>>1)&3)
  auto stage = [&](int kk, int buf) {
    const int k0 = kk * 32;
    const int sw = (srow >> 1) & 3;
    const int gc = ((lane & 3) ^ sw) * 8;
    #pragma unroll
    for (int c = 0; c < 2; ++c) {
      const int r = wid * 32 + c * 16;
      const unsigned short* sa = A  + (size_t)(m0 + r + srow) * 512 + k0 + gc;
      const unsigned short* sb = Bm + (size_t)(n0 + r + srow) * 512 + k0 + gc;
      __builtin_amdgcn_global_load_lds((const AS1 void*)sa, (AS3 void*)&ldsA[buf][r * 32], 16, 0, 0);
      __builtin_amdgcn_global_load_lds((const AS1 void*)sb, (AS3 void*)&ldsB[buf][r * 32], 16, 0, 0);
    }
  };

  stage(0, 0);
  __syncthreads();

  const int rl = lane & 15;
  const int kb = lane >> 4;
  const int rsw = kb ^ ((rl >> 1) & 3);

  for (int kk = 0; kk < NK; ++kk) {
    const int buf = kk & 1;
    if (kk + 1 < NK) stage(kk + 1, buf ^ 1);
    const bf16x8* Af = (const bf16x8*)&ldsA[buf][0];
    const bf16x8* Bf = (const bf16x8*)&ldsB[buf][0];
    bf16x8 av[4], bv[4];
    #pragma unroll
    for (int mi = 0; mi < 4; ++mi) av[mi] = Af[(wm * 64 + mi * 16 + rl) * 4 + rsw];
    #pragma unroll
    for (int ni = 0; ni < 4; ++ni) bv[ni] = Bf[(wn * 64 + ni * 16 + rl) * 4 + rsw];
    #pragma unroll
    for (int mi = 0; mi < 4; ++mi)
      #pragma unroll
      for (int ni = 0; ni < 4; ++ni)
        acc[mi][ni] = __builtin_amdgcn_mfma_f32_16x16x32_bf16(av[mi], bv[ni], acc[mi][ni], 0, 0, 0);
    __syncthreads();
  }

  const int rb = kb * 4;
  #pragma unroll
  for (int mi = 0; mi < 4; ++mi)
    #pragma unroll
    for (int ni = 0; ni < 4; ++ni) {
      size_t rrow = (size_t)(m0 + wm * 64 + mi * 16 + rb);
      size_t col = (size_t)(n0 + wn * 64 + ni * 16 + rl);
      #pragma unroll
      for (int j = 0; j < 4; ++j)
        __builtin_nontemporal_store(acc[mi][ni][j], &C[(rrow + j) * (size_t)V_ + col]);
    }

  // ---- per-tile row max / sum-exp partials ----
  float tm[4][4];
  #pragma unroll
  for (int mi = 0; mi < 4; ++mi)
    #pragma unroll
    for (int j = 0; j < 4; ++j) {
      float m = fmaxf(fmaxf(acc[mi][0][j], acc[mi][1][j]), fmaxf(acc[mi][2][j], acc[mi][3][j]));
      m = fmaxf(m, __shfl_xor(m, 1)); m = fmaxf(m, __shfl_xor(m, 2));
      m = fmaxf(m, __shfl_xor(m, 4)); m = fmaxf(m, __shfl_xor(m, 8));
      tm[mi][j] = m;
    }
  if (rl == 0) {
    #pragma unroll
    for (int mi = 0; mi < 4; ++mi)
      #pragma unroll
      for (int j = 0; j < 4; ++j)
        smax[wn][wm * 64 + mi * 16 + kb * 4 + j] = tm[mi][j];
  }
  __syncthreads();
  float ts[4][4];
  #pragma unroll
  for (int mi = 0; mi < 4; ++mi)
    #pragma unroll
    for (int j = 0; j < 4; ++j) {
      int rlocal = wm * 64 + mi * 16 + kb * 4 + j;
      float M = fmaxf(smax[0][rlocal], smax[1][rlocal]);
      float s = __expf(acc[mi][0][j] - M) + __expf(acc[mi][1][j] - M) +
                __expf(acc[mi][2][j] - M) + __expf(acc[mi][3][j] - M);
      s += __shfl_xor(s, 1); s += __shfl_xor(s, 2);
      s += __shfl_xor(s, 4); s += __shfl_xor(s, 8);
      ts[mi][j] = s;
    }
  if (rl == 0) {
    #pragma unroll
    for (int mi = 0; mi < 4; ++mi)
      #pragma unroll
      for (int j = 0; j < 4; ++j)
        ssum[wn][wm * 64 + mi * 16 + kb * 4 + j] = ts[mi][j];
  }
  __syncthreads();
  if (tid < 128) {
    float M = fmaxf(smax[0][tid], smax[1][tid]);
    float S = ssum[0][tid] + ssum[1][tid];
    pmax[(size_t)(m0 + tid) * 256 + blockIdx.y] = M;
    psum[(size_t)(m0 + tid) * 256 + blockIdx.y] = S;
  }
}

// ---------------- finish: lse from partials, then C[row] -= lse
__global__ __launch_bounds__(256) void softmax_finish_kernel(
    float* __restrict__ C, const float* __restrict__ pmax, const float* __restrict__ psum) {
  const size_t row = blockIdx.x;
  const int tid = threadIdx.x, lane = tid & 63, wid = tid >> 6;
  __shared__ float red[4];

  float pm = (tid < 250) ? pmax[row * 256 + tid] : -INFINITY;
  float ps = (tid < 250) ? psum[row * 256 + tid] : 0.f;

  float m = pm;
  #pragma unroll
  for (int off = 32; off > 0; off >>= 1) m = fmaxf(m, __shfl_xor(m, off));
  if (lane == 0) red[wid] = m;
  __syncthreads();
  m = fmaxf(fmaxf(red[0], red[1]), fmaxf(red[2], red[3]));
  __syncthreads();

  float s = (tid < 250) ? ps * __expf(pm - m) : 0.f;
  #pragma unroll
  for (int off = 32; off > 0; off >>= 1) s += __shfl_xor(s, off);
  if (lane == 0) red[wid] = s;
  __syncthreads();
  s = red[0] + red[1] + red[2] + red[3];
  const float lse = m + logf(s);

  f32x4* p4 = (f32x4*)(C + row * (size_t)V_);
  for (int i = tid; i < 8000; i += 256) {
    f32x4 v = p4[i];
    v -= lse;
    __builtin_nontemporal_store(v, &p4[i]);
  }
}

extern "C" void kernel_launch(void* const* d_in, const int* in_sizes, int n_in,
                              void* d_out, int out_size, void* d_ws, size_t ws_size,
                              hipStream_t stream) {
  const int*   dst  = (const int*)d_in[0];
  const float* E    = (const float*)d_in[1];
  const float* Wih  = (const float*)d_in[2];
  const float* Whh  = (const float*)d_in[3];
  const float* bih  = (const float*)d_in[4];
  const float* bhh  = (const float*)d_in[5];
  const float* h0   = (const float*)d_in[6];
  const float* c0   = (const float*)d_in[7];
  const float* out0 = (const float*)d_in[8];
  float* C = (float*)d_out;

  char* ws = (char*)d_ws;
  unsigned short* Ebf   = (unsigned short*)(ws);                      // 32.77 MB
  unsigned short* preA3 = (unsigned short*)(ws + (size_t)33554432);   // 16.78 MB
  unsigned short* Wrs   = (unsigned short*)(ws + (size_t)50331648);   // 2.10 MB
  unsigned short* embbf = (unsigned short*)(ws + (size_t)52428800);   // pre-phase
  float*          pmax  = (float*)(ws + (size_t)52428800);            // post-phase 4.19 MB
  unsigned short* W1bf  = (unsigned short*)(ws + (size_t)56623104);   // pre-phase
  float*          psum  = (float*)(ws + (size_t)56623104);            // post-phase 4.19 MB
  unsigned short* Abf   = (unsigned short*)(ws + (size_t)60817408);   // 4.19 MB
  unsigned int*   htag  = (unsigned int*)(ws + (size_t)65011712);     // 128 KB tagged h

  (void)hipMemsetAsync(htag, 0xFF, 131072, stream);   // tags 0xFFFF: never match

  // --- precompute ---
  embed_bf_kernel<<<dim3(T_ * B_), dim3(64), 0, stream>>>(dst, E, embbf);
  cvt_kernel<<<dim3(2048), dim3(256), 0, stream>>>(E, Ebf, V_ * D_ / 4);
  cvt_w1_kernel<<<dim3(256), dim3(256), 0, stream>>>(Wih, W1bf, 2048 * 512 / 4);
  wr_prep_swz_kernel<<<dim3(256), dim3(256), 0, stream>>>(Wih, Whh, Wrs, 2048 * 512 / 4);
  seed_h0_kernel<<<dim3(64), dim3(256), 0, stream>>>(h0, htag);

  gemm_pre_kernel<<<dim3(2048 / 128, 4096 / 128), dim3(256), 0, stream>>>(embbf, W1bf, bih, bhh, preA3);
  delta0_kernel<<<dim3(2048), dim3(256), 0, stream>>>(Wih, out0, h0, preA3);

  // --- full recurrence, one launch, 16 blocks, tagged phased exchange ---
  lstm_persist_tag_kernel<<<dim3(16), dim3(1024), 0, stream>>>(Wrs, preA3, c0, htag, Abf);

  // --- projection + fused softmax partials ---
  gemm_kernel<<<dim3(32, 250), dim3(256), 0, stream>>>(Abf, Ebf, C, pmax, psum);
  softmax_finish_kernel<<<dim3(B_ * T_), dim3(256), 0, stream>>>(C, pmax, psum);
}

// Round 11
// 1082.159 us; speedup vs baseline: 1.2061x; 1.2061x over previous
//
#include <hip/hip_runtime.h>
#include <hip/hip_bf16.h>
#include <math.h>

#define B_ 32
#define T_ 128
#define V_ 32000
#define D_ 512
#define H_ 512

typedef __attribute__((ext_vector_type(8))) short bf16x8;
typedef __attribute__((ext_vector_type(4))) float f32x4;
typedef __attribute__((ext_vector_type(2))) unsigned long long u64x2;

#define AS1 __attribute__((address_space(1)))
#define AS3 __attribute__((address_space(3)))

__device__ __forceinline__ unsigned short f2bf(float x) {
  unsigned int b = __float_as_uint(x);
  return (unsigned short)((b + 0x7FFFu + ((b >> 16) & 1u)) >> 16);
}
__device__ __forceinline__ float bf2f(unsigned short u) {
  return __uint_as_float(((unsigned int)u) << 16);
}
__device__ __forceinline__ float sigm(float x) { return 1.0f / (1.0f + __expf(-x)); }
__device__ __forceinline__ float tanh_fast(float x) { return 1.0f - 2.0f / (__expf(2.0f * x) + 1.0f); }

__device__ __forceinline__ unsigned long long ald64(const unsigned long long* p) {
  return __hip_atomic_load(p, __ATOMIC_RELAXED, __HIP_MEMORY_SCOPE_AGENT);
}
__device__ __forceinline__ unsigned ald32(const unsigned* p) {
  return __hip_atomic_load(p, __ATOMIC_RELAXED, __HIP_MEMORY_SCOPE_AGENT);
}

// ---------------- embedding gather -> bf16
__global__ __launch_bounds__(64) void embed_bf_kernel(const int* __restrict__ dst,
                                                      const float* __restrict__ E,
                                                      unsigned short* __restrict__ embbf) {
  int rt = blockIdx.x;           // t*32 + b
  int t = rt >> 5, b = rt & 31;
  int v = dst[b * T_ + t];
  const float4* src = (const float4*)(E + (size_t)v * D_);
  ushort4* d = (ushort4*)(embbf + (size_t)rt * D_);
  #pragma unroll
  for (int r = 0; r < 2; ++r) {
    float4 x = src[threadIdx.x + r * 64];
    ushort4 o; o.x = f2bf(x.x); o.y = f2bf(x.y); o.z = f2bf(x.z); o.w = f2bf(x.w);
    d[threadIdx.x + r * 64] = o;
  }
}

// ---------------- generic f32 -> bf16
__global__ void cvt_kernel(const float* __restrict__ in, unsigned short* __restrict__ out, int n4) {
  int stride = gridDim.x * blockDim.x;
  for (int i = blockIdx.x * blockDim.x + threadIdx.x; i < n4; i += stride) {
    float4 v = ((const float4*)in)[i];
    ushort4 o; o.x = f2bf(v.x); o.y = f2bf(v.y); o.z = f2bf(v.z); o.w = f2bf(v.w);
    ((ushort4*)out)[i] = o;
  }
}

// ---------------- W1bf[r][c] = bf16(Wih[r][c]), c<512 (row stride 1024)
__global__ void cvt_w1_kernel(const float* __restrict__ Wih, unsigned short* __restrict__ W1bf, int n4) {
  int stride = gridDim.x * blockDim.x;
  for (int i = blockIdx.x * blockDim.x + threadIdx.x; i < n4; i += stride) {
    int flat = i * 4;
    int r = flat >> 9, c = flat & 511;
    float4 v = *(const float4*)(Wih + (size_t)r * 1024 + c);
    ushort4 o; o.x = f2bf(v.x); o.y = f2bf(v.y); o.z = f2bf(v.z); o.w = f2bf(v.w);
    ((ushort4*)W1bf)[i] = o;
  }
}

// ---------------- Wr rows reordered for lane-local epilogue:
// out_row = bid*128 + k_loc*4 + gate  (gate = grow>>9, kg = grow&511)
// per-row 16B-chunk swizzle: chunk ^= (out_row & 7)
__global__ void wr_prep_swz_kernel(const float* __restrict__ Wih, const float* __restrict__ Whh,
                                   unsigned short* __restrict__ Wrs, int n4) {
  int stride = gridDim.x * blockDim.x;
  for (int i = blockIdx.x * blockDim.x + threadIdx.x; i < n4; i += stride) {
    int flat = i * 4;
    int grow = flat >> 9, k = flat & 511;
    float4 a = *(const float4*)(Wih + (size_t)grow * 1024 + 512 + k);
    float4 b = ((const float4*)Whh)[i];
    ushort4 o;
    o.x = f2bf(a.x + b.x); o.y = f2bf(a.y + b.y); o.z = f2bf(a.z + b.z); o.w = f2bf(a.w + b.w);
    int gate = grow >> 9, kgl = grow & 511;
    int orow = (kgl >> 5) * 128 + (kgl & 31) * 4 + gate;
    int chunk = (k >> 3) ^ (orow & 7);
    *(ushort4*)(Wrs + (size_t)orow * 512 + chunk * 8 + (k & 7)) = o;
  }
}

// ---------------- pre-GEMM: preA3[t][kg][b][gate] = bf16(emb . W1 + bias)
__global__ __launch_bounds__(256) void gemm_pre_kernel(
    const unsigned short* __restrict__ A,
    const unsigned short* __restrict__ Bm,
    const float* __restrict__ bih, const float* __restrict__ bhh,
    unsigned short* __restrict__ preA3)
{
  __shared__ unsigned short ldsA[2][128 * 32];
  __shared__ unsigned short ldsB[2][128 * 32];
  const int tid = threadIdx.x;
  const int lane = tid & 63;
  const int wid = tid >> 6;
  const int wm = wid >> 1, wn = wid & 1;
  const int m0 = blockIdx.y * 128;
  const int n0 = blockIdx.x * 128;
  const int srow = lane >> 2;
  const int scol = (lane & 3) * 8;

  f32x4 acc[4][4] = {};
  const int NK = 512 / 32;

  auto stage = [&](int kk, int buf) {
    const int k0 = kk * 32;
    #pragma unroll
    for (int c = 0; c < 2; ++c) {
      const int r = wid * 32 + c * 16;
      const unsigned short* sa = A  + (size_t)(m0 + r + srow) * 512 + k0 + scol;
      const unsigned short* sb = Bm + (size_t)(n0 + r + srow) * 512 + k0 + scol;
      __builtin_amdgcn_global_load_lds((const AS1 void*)sa, (AS3 void*)&ldsA[buf][r * 32], 16, 0, 0);
      __builtin_amdgcn_global_load_lds((const AS1 void*)sb, (AS3 void*)&ldsB[buf][r * 32], 16, 0, 0);
    }
  };

  stage(0, 0);
  __syncthreads();

  const int rl = lane & 15;
  const int kb = lane >> 4;

  for (int kk = 0; kk < NK; ++kk) {
    const int buf = kk & 1;
    if (kk + 1 < NK) stage(kk + 1, buf ^ 1);
    const bf16x8* Af = (const bf16x8*)&ldsA[buf][0];
    const bf16x8* Bf = (const bf16x8*)&ldsB[buf][0];
    bf16x8 av[4], bv[4];
    #pragma unroll
    for (int mi = 0; mi < 4; ++mi) av[mi] = Af[(wm * 64 + mi * 16 + rl) * 4 + kb];
    #pragma unroll
    for (int ni = 0; ni < 4; ++ni) bv[ni] = Bf[(wn * 64 + ni * 16 + rl) * 4 + kb];
    #pragma unroll
    for (int mi = 0; mi < 4; ++mi)
      #pragma unroll
      for (int ni = 0; ni < 4; ++ni)
        acc[mi][ni] = __builtin_amdgcn_mfma_f32_16x16x32_bf16(av[mi], bv[ni], acc[mi][ni], 0, 0, 0);
    __syncthreads();
  }

  const int rb = (lane >> 4) * 4;
  #pragma unroll
  for (int mi = 0; mi < 4; ++mi)
    #pragma unroll
    for (int ni = 0; ni < 4; ++ni) {
      int mbase = m0 + wm * 64 + mi * 16 + rb;
      int col   = n0 + wn * 64 + ni * 16 + rl;
      int gate = col >> 9, kg = col & 511;
      int tt = mbase >> 5, bb0 = mbase & 31;
      float bb = bih[col] + bhh[col];
      #pragma unroll
      for (int j = 0; j < 4; ++j)
        preA3[(((size_t)tt * 512 + kg) * 32 + bb0 + j) * 4 + gate] = f2bf(acc[mi][ni][j] + bb);
    }
}

// ---------------- preA3[t=0][kg][:][gate] += (out0 - h0) @ W2^T  (row r = grow)
__global__ __launch_bounds__(256) void delta0_kernel(const float* __restrict__ Wih,
                                                     const float* __restrict__ out0,
                                                     const float* __restrict__ h0,
                                                     unsigned short* __restrict__ preA3) {
  const int r = blockIdx.x;
  const int tid = threadIdx.x;
  const int b = tid >> 3, seg = tid & 7;
  __shared__ float red[32][9];
  const float4* o4 = (const float4*)(out0 + (size_t)b * 512 + seg * 64);
  const float4* h4 = (const float4*)(h0 + (size_t)b * 512 + seg * 64);
  const float4* w4 = (const float4*)(Wih + (size_t)r * 1024 + 512 + seg * 64);
  float s = 0.f;
  #pragma unroll
  for (int j = 0; j < 16; ++j) {
    float4 o = o4[j], h = h4[j], w = w4[j];
    s += (o.x - h.x) * w.x + (o.y - h.y) * w.y + (o.z - h.z) * w.z + (o.w - h.w) * w.w;
  }
  red[b][seg] = s;
  __syncthreads();
  if (tid < 32) {
    float t = 0.f;
    #pragma unroll
    for (int j = 0; j < 8; ++j) t += red[tid][j];
    int gate = r >> 9, kgl = r & 511;
    unsigned short* p = preA3 + ((size_t)kgl * 32 + tid) * 4 + gate;
    *p = f2bf(bf2f(*p) + t);
  }
}

// ---------------- persistent LSTM, 16 blocks x 1024 threads, ROLE-SPLIT phases.
// Phase p (t=p>>1, ph=p&1): waves of half ph COMPUTE step t for batches
// ph*16..ph*16+15 (reading hexch[p&1]); waves of half ph^1 STAGE their own
// next-phase h into hexch[(p+1)&1] (per-lane flag poll -> agent load ->
// swizzled ds_write). One __syncthreads per phase; flag stored after the
// barrier (vmcnt drained) as in R9's proven protocol.
__global__ __launch_bounds__(1024) void lstm_persist_rs_kernel(
    const unsigned short* __restrict__ Wrs,   // [2048][512] reordered+swizzled bf16
    const unsigned short* __restrict__ preA3, // [T][512][32][4] bf16 (bias folded)
    const float* __restrict__ c0,             // [32][512] f32
    unsigned short* __restrict__ hb0,         // [32][512] bf16 (h0 at entry)
    unsigned short* __restrict__ hb1,         // pong
    unsigned short* __restrict__ Abf,         // [B*T][512] bf16
    unsigned int* __restrict__ flags)         // [2][16] x 64B lines, zeroed each call
{
  __shared__ unsigned short wlds[128 * 512];            // 128 KB, resident
  __shared__ __align__(16) char hexch[2][16 * 1024];    // 2 x 16 KB half-batch h tiles
  const int tid = threadIdx.x, bid = blockIdx.x;
  const int lane = tid & 63, wid = tid >> 6;

  // stage 128 reordered W rows once (pre-swizzled source, linear LDS dest)
  #pragma unroll
  for (int it = 0; it < 8; ++it) {
    int r = it * 16 + wid;
    const unsigned short* src = Wrs + ((size_t)bid * 128 + r) * 512 + lane * 8;
    __builtin_amdgcn_global_load_lds((const AS1 void*)src, (AS3 void*)&wlds[r * 512], 16, 0, 0);
  }

  const int myhalf = wid >> 3;               // waves 0-7: half A, 8-15: half B
  const int rt = wid & 7;
  const int q = lane >> 4, rl = lane & 15;
  const int kg = bid * 32 + rt * 4 + q;      // this lane's k-slot
  const int b = myhalf * 16 + rl;            // this lane's batch
  float c_reg = c0[(size_t)b * 512 + kg];

  const int row = rt * 16 + rl;
  const char* wbase = (const char*)wlds + row * 1024;
  const int rx = (row & 7) << 4;
  const int hx = (rl & 7) << 4;

  // stager role constants (per-lane): row sr (0..15 within own half), 32B chunk sc
  const int sw = wid & 7;
  const int sr = sw * 2 + (lane >> 5);
  const int sc = lane & 31;
  const int sblk = sc >> 1;                  // producer block of this 32B
  const int srx = (sr & 7) << 4;
  const int sofs = sc * 32;

  // prologue: half A stages its h0 into hexch[0]
  if (myhalf == 0) {
    const unsigned long long* src =
        (const unsigned long long*)(hb0 + (size_t)sr * 512) + sc * 4;
    unsigned long long d0 = ald64(src + 0), d1 = ald64(src + 1);
    unsigned long long d2 = ald64(src + 2), d3 = ald64(src + 3);
    char* dst = hexch[0] + sr * 1024;
    u64x2 w0; w0[0] = d0; w0[1] = d1;
    u64x2 w1; w1[0] = d2; w1[1] = d3;
    *(u64x2*)(dst + (sofs ^ srx)) = w0;
    *(u64x2*)(dst + ((sofs + 16) ^ srx)) = w1;
  }
  __syncthreads();   // drains W staging (vmcnt) + prologue LDS writes

  for (int p = 0; p < 2 * T_; ++p) {
    const int t = p >> 1, ph = p & 1, buf = p & 1;

    if (myhalf == ph) {
      // ---- COMPUTE step t for own batches
      unsigned long long pre =
          *(const unsigned long long*)(preA3 + (((size_t)t * 512 + kg) * 32 + b) * 4);
      const char* hbase = hexch[buf] + rl * 1024;
      f32x4 acc = {}, acc2 = {};
      #pragma unroll
      for (int kk = 0; kk < 16; kk += 2) {
        int k0 = kk * 32 + q * 8;
        int k1 = k0 + 32;
        bf16x8 av0 = *(const bf16x8*)(wbase + ((k0 * 2) ^ rx));
        bf16x8 bv0 = *(const bf16x8*)(hbase + ((k0 * 2) ^ hx));
        bf16x8 av1 = *(const bf16x8*)(wbase + ((k1 * 2) ^ rx));
        bf16x8 bv1 = *(const bf16x8*)(hbase + ((k1 * 2) ^ hx));
        acc  = __builtin_amdgcn_mfma_f32_16x16x32_bf16(av0, bv0, acc, 0, 0, 0);
        acc2 = __builtin_amdgcn_mfma_f32_16x16x32_bf16(av1, bv1, acc2, 0, 0, 0);
      }
      // lane-local epilogue: acc[j] = gate j pre-activation for (kg, b)
      float g0 = acc[0] + acc2[0] + bf2f((unsigned short)(pre));
      float g1 = acc[1] + acc2[1] + bf2f((unsigned short)(pre >> 16));
      float g2 = acc[2] + acc2[2] + bf2f((unsigned short)(pre >> 32));
      float g3 = acc[3] + acc2[3] + bf2f((unsigned short)(pre >> 48));
      float iv = sigm(g0), fv = sigm(g1), gv = tanh_fast(g2), ov = sigm(g3);
      float cn = fv * c_reg + iv * gv;
      c_reg = cn;
      float hn = ov * tanh_fast(cn);
      int hv = (int)f2bf(hn);
      int nb = __shfl(hv, lane + 16);        // partner k-slot (q+1)
      if ((q & 1) == 0) {
        unsigned pair = (unsigned)hv | ((unsigned)nb << 16);
        if (t != T_ - 1) {
          unsigned short* hout = ((t + 1) & 1) ? hb1 : hb0;
          __hip_atomic_store((unsigned int*)(hout + (size_t)b * 512 + kg), pair,
                             __ATOMIC_RELAXED, __HIP_MEMORY_SCOPE_AGENT);
        }
        *(unsigned*)(Abf + ((size_t)b * T_ + t) * 512 + kg) = pair;
      }
    } else if (p + 1 < 2 * T_) {
      // ---- STAGE own half's h for phase p+1 (step t2)
      const int t2 = (p + 1) >> 1;
      if (t2 > 0) {
        const unsigned* fl = &flags[(myhalf * 16 + sblk) * 16];
        unsigned spins = 0;
        while (ald32(fl) < (unsigned)t2) {
          if (++spins > 1000000u) break;     // bailout: fail validation, don't hang
        }
      }
      const unsigned short* hsrc = (t2 & 1) ? hb1 : hb0;
      const unsigned long long* src =
          (const unsigned long long*)(hsrc + (size_t)(myhalf * 16 + sr) * 512) + sc * 4;
      unsigned long long d0 = ald64(src + 0), d1 = ald64(src + 1);
      unsigned long long d2 = ald64(src + 2), d3 = ald64(src + 3);
      char* dst = hexch[buf ^ 1] + sr * 1024;
      u64x2 w0; w0[0] = d0; w0[1] = d1;
      u64x2 w1; w1[0] = d2; w1[1] = d3;
      *(u64x2*)(dst + (sofs ^ srx)) = w0;
      *(u64x2*)(dst + ((sofs + 16) ^ srx)) = w1;
    }

    __syncthreads();   // publishes drained (vmcnt 0) + LDS stage visible

    if (tid == ph * 512)   // first thread of the computing half
      __hip_atomic_store(&flags[(ph * 16 + bid) * 16], (unsigned)(t + 1),
                         __ATOMIC_RELAXED, __HIP_MEMORY_SCOPE_AGENT);
  }
}

// ---------------- projection GEMM (swizzled LDS, nt C stores) + softmax partials
// grid (32 m-tiles [x, fast], 250 n-tiles [y]) -> consecutive blocks share B panel.
__global__ __launch_bounds__(256) void gemm_kernel(
    const unsigned short* __restrict__ A,
    const unsigned short* __restrict__ Bm,
    float* __restrict__ C,
    float* __restrict__ pmax, float* __restrict__ psum)
{
  __shared__ unsigned short ldsA[2][128 * 32];
  __shared__ unsigned short ldsB[2][128 * 32];
  __shared__ float smax[2][128];
  __shared__ float ssum[2][128];
  const int tid = threadIdx.x;
  const int lane = tid & 63;
  const int wid = tid >> 6;
  const int wm = wid >> 1, wn = wid & 1;
  const int m0 = blockIdx.x * 128;
  const int n0 = blockIdx.y * 128;
  const int srow = lane >> 2;

  f32x4 acc[4][4] = {};
  const int NK = 512 / 32;

  // swizzle: LDS chunk c of row r holds global chunk c ^ ((r>>1)&3)
  auto stage = [&](int kk, int buf) {
    const int k0 = kk * 32;
    const int sw = (srow >> 1) & 3;
    const int gc = ((lane & 3) ^ sw) * 8;
    #pragma unroll
    for (int c = 0; c < 2; ++c) {
      const int r = wid * 32 + c * 16;
      const unsigned short* sa = A  + (size_t)(m0 + r + srow) * 512 + k0 + gc;
      const unsigned short* sb = Bm + (size_t)(n0 + r + srow) * 512 + k0 + gc;
      __builtin_amdgcn_global_load_lds((const AS1 void*)sa, (AS3 void*)&ldsA[buf][r * 32], 16, 0, 0);
      __builtin_amdgcn_global_load_lds((const AS1 void*)sb, (AS3 void*)&ldsB[buf][r * 32], 16, 0, 0);
    }
  };

  stage(0, 0);
  __syncthreads();

  const int rl = lane & 15;
  const int kb = lane >> 4;
  const int rsw = kb ^ ((rl >> 1) & 3);

  for (int kk = 0; kk < NK; ++kk) {
    const int buf = kk & 1;
    if (kk + 1 < NK) stage(kk + 1, buf ^ 1);
    const bf16x8* Af = (const bf16x8*)&ldsA[buf][0];
    const bf16x8* Bf = (const bf16x8*)&ldsB[buf][0];
    bf16x8 av[4], bv[4];
    #pragma unroll
    for (int mi = 0; mi < 4; ++mi) av[mi] = Af[(wm * 64 + mi * 16 + rl) * 4 + rsw];
    #pragma unroll
    for (int ni = 0; ni < 4; ++ni) bv[ni] = Bf[(wn * 64 + ni * 16 + rl) * 4 + rsw];
    #pragma unroll
    for (int mi = 0; mi < 4; ++mi)
      #pragma unroll
      for (int ni = 0; ni < 4; ++ni)
        acc[mi][ni] = __builtin_amdgcn_mfma_f32_16x16x32_bf16(av[mi], bv[ni], acc[mi][ni], 0, 0, 0);
    __syncthreads();
  }

  const int rb = kb * 4;
  #pragma unroll
  for (int mi = 0; mi < 4; ++mi)
    #pragma unroll
    for (int ni = 0; ni < 4; ++ni) {
      size_t rrow = (size_t)(m0 + wm * 64 + mi * 16 + rb);
      size_t col = (size_t)(n0 + wn * 64 + ni * 16 + rl);
      #pragma unroll
      for (int j = 0; j < 4; ++j)
        __builtin_nontemporal_store(acc[mi][ni][j], &C[(rrow + j) * (size_t)V_ + col]);
    }

  // ---- per-tile row max / sum-exp partials ----
  float tm[4][4];
  #pragma unroll
  for (int mi = 0; mi < 4; ++mi)
    #pragma unroll
    for (int j = 0; j < 4; ++j) {
      float m = fmaxf(fmaxf(acc[mi][0][j], acc[mi][1][j]), fmaxf(acc[mi][2][j], acc[mi][3][j]));
      m = fmaxf(m, __shfl_xor(m, 1)); m = fmaxf(m, __shfl_xor(m, 2));
      m = fmaxf(m, __shfl_xor(m, 4)); m = fmaxf(m, __shfl_xor(m, 8));
      tm[mi][j] = m;
    }
  if (rl == 0) {
    #pragma unroll
    for (int mi = 0; mi < 4; ++mi)
      #pragma unroll
      for (int j = 0; j < 4; ++j)
        smax[wn][wm * 64 + mi * 16 + kb * 4 + j] = tm[mi][j];
  }
  __syncthreads();
  float ts[4][4];
  #pragma unroll
  for (int mi = 0; mi < 4; ++mi)
    #pragma unroll
    for (int j = 0; j < 4; ++j) {
      int rlocal = wm * 64 + mi * 16 + kb * 4 + j;
      float M = fmaxf(smax[0][rlocal], smax[1][rlocal]);
      float s = __expf(acc[mi][0][j] - M) + __expf(acc[mi][1][j] - M) +
                __expf(acc[mi][2][j] - M) + __expf(acc[mi][3][j] - M);
      s += __shfl_xor(s, 1); s += __shfl_xor(s, 2);
      s += __shfl_xor(s, 4); s += __shfl_xor(s, 8);
      ts[mi][j] = s;
    }
  if (rl == 0) {
    #pragma unroll
    for (int mi = 0; mi < 4; ++mi)
      #pragma unroll
      for (int j = 0; j < 4; ++j)
        ssum[wn][wm * 64 + mi * 16 + kb * 4 + j] = ts[mi][j];
  }
  __syncthreads();
  if (tid < 128) {
    float M = fmaxf(smax[0][tid], smax[1][tid]);
    float S = ssum[0][tid] + ssum[1][tid];
    pmax[(size_t)(m0 + tid) * 256 + blockIdx.y] = M;
    psum[(size_t)(m0 + tid) * 256 + blockIdx.y] = S;
  }
}

// ---------------- finish: lse from partials, then C[row] -= lse
__global__ __launch_bounds__(256) void softmax_finish_kernel(
    float* __restrict__ C, const float* __restrict__ pmax, const float* __restrict__ psum) {
  const size_t row = blockIdx.x;
  const int tid = threadIdx.x, lane = tid & 63, wid = tid >> 6;
  __shared__ float red[4];

  float pm = (tid < 250) ? pmax[row * 256 + tid] : -INFINITY;
  float ps = (tid < 250) ? psum[row * 256 + tid] : 0.f;

  float m = pm;
  #pragma unroll
  for (int off = 32; off > 0; off >>= 1) m = fmaxf(m, __shfl_xor(m, off));
  if (lane == 0) red[wid] = m;
  __syncthreads();
  m = fmaxf(fmaxf(red[0], red[1]), fmaxf(red[2], red[3]));
  __syncthreads();

  float s = (tid < 250) ? ps * __expf(pm - m) : 0.f;
  #pragma unroll
  for (int off = 32; off > 0; off >>= 1) s += __shfl_xor(s, off);
  if (lane == 0) red[wid] = s;
  __syncthreads();
  s = red[0] + red[1] + red[2] + red[3];
  const float lse = m + logf(s);

  f32x4* p4 = (f32x4*)(C + row * (size_t)V_);
  for (int i = tid; i < 8000; i += 256) {
    f32x4 v = p4[i];
    v -= lse;
    __builtin_nontemporal_store(v, &p4[i]);
  }
}

extern "C" void kernel_launch(void* const* d_in, const int* in_sizes, int n_in,
                              void* d_out, int out_size, void* d_ws, size_t ws_size,
                              hipStream_t stream) {
  const int*   dst  = (const int*)d_in[0];
  const float* E    = (const float*)d_in[1];
  const float* Wih  = (const float*)d_in[2];
  const float* Whh  = (const float*)d_in[3];
  const float* bih  = (const float*)d_in[4];
  const float* bhh  = (const float*)d_in[5];
  const float* h0   = (const float*)d_in[6];
  const float* c0   = (const float*)d_in[7];
  const float* out0 = (const float*)d_in[8];
  float* C = (float*)d_out;

  char* ws = (char*)d_ws;
  unsigned short* Ebf   = (unsigned short*)(ws);                      // 32.77 MB
  unsigned short* preA3 = (unsigned short*)(ws + (size_t)33554432);   // 16.78 MB
  unsigned short* Wrs   = (unsigned short*)(ws + (size_t)50331648);   // 2.10 MB
  unsigned short* embbf = (unsigned short*)(ws + (size_t)52428800);   // pre-phase
  float*          pmax  = (float*)(ws + (size_t)52428800);            // post-phase 4.19 MB
  unsigned short* W1bf  = (unsigned short*)(ws + (size_t)56623104);   // pre-phase
  float*          psum  = (float*)(ws + (size_t)56623104);            // post-phase 4.19 MB
  unsigned short* Abf   = (unsigned short*)(ws + (size_t)60817408);   // 4.19 MB
  unsigned short* hb0   = (unsigned short*)(ws + (size_t)65011712);   // 32 KB
  unsigned short* hb1   = (unsigned short*)(ws + (size_t)65044480);   // 32 KB
  unsigned int*   flg   = (unsigned int*)(ws + (size_t)65077248);     // 2 KB (2 x 16 x 64B)

  (void)hipMemsetAsync(flg, 0, 2048, stream);

  // --- precompute ---
  embed_bf_kernel<<<dim3(T_ * B_), dim3(64), 0, stream>>>(dst, E, embbf);
  cvt_kernel<<<dim3(2048), dim3(256), 0, stream>>>(E, Ebf, V_ * D_ / 4);
  cvt_w1_kernel<<<dim3(256), dim3(256), 0, stream>>>(Wih, W1bf, 2048 * 512 / 4);
  wr_prep_swz_kernel<<<dim3(256), dim3(256), 0, stream>>>(Wih, Whh, Wrs, 2048 * 512 / 4);

  gemm_pre_kernel<<<dim3(2048 / 128, 4096 / 128), dim3(256), 0, stream>>>(embbf, W1bf, bih, bhh, preA3);
  delta0_kernel<<<dim3(2048), dim3(256), 0, stream>>>(Wih, out0, h0, preA3);
  cvt_kernel<<<dim3(16), dim3(256), 0, stream>>>(h0, hb0, B_ * H_ / 4);

  // --- full recurrence, one launch, 16 blocks, role-split phases ---
  lstm_persist_rs_kernel<<<dim3(16), dim3(1024), 0, stream>>>(Wrs, preA3, c0, hb0, hb1, Abf, flg);

  // --- projection + fused softmax partials ---
  gemm_kernel<<<dim3(32, 250), dim3(256), 0, stream>>>(Abf, Ebf, C, pmax, psum);
  softmax_finish_kernel<<<dim3(B_ * T_), dim3(256), 0, stream>>>(C, pmax, psum);
}